// Round 15
// baseline (224.112 us; speedup 1.0000x reference)
//
#include <hip/hip_runtime.h>
#include <math.h>

// CRITICAL: ban FMA contraction file-wide. 1-ulp iou shifts flip near-tie
// argmaxes vs numpy's correctly-rounded ref (rounds 2-4, absmax 69).
#pragma clang fp contract(off)

// Shapes: B=64, N=100, A=8732.
// Out layout (f32 flat): [0,BA) labels | [BA,5BA) boxes | [5BA,6BA) mask
// FUSED path (ws_size >= 51200): colmax u64[B*N] in d_ws; iou_pass writes
// the final outputs directly; override_kernel fixes overridden anchors.
// FALLBACK path: colmax at out+BA, slot in mask region, scatter+encode (r12).

#define AA 8732
#define NN 100
#define BB 64
#define EPS_F 1e-6f
#define OVR_FLAG 0x10000
#define POS_BIT  0x8000
// One-sided-bound margins (HW-validated r8/r10/r11/r12):
// DEFL deflates filter bounds (rcp err 1.8e-7 / snapshot slack + margin);
// FDEFL covers the two f32 product roundings in cross-mult compares.
// R14 BUG (fixed here): the colmax-hi snapshot was used UNDEFLATED — warmed
// genuine iou bits can round s.t. fl(iou*U) > I by 1 ulp, dropping a
// tied-lower-index winner (tie-break flip -> wrong override -> absmax 79).
// Every filter value must be deflated at the read site.
#define DEFL  0.9999995f
#define FDEFL 0.9999996f

__constant__ int FM_SIZE[6] = {38, 19, 10, 5, 3, 1};
__constant__ int FM_NF[6]   = {4, 6, 6, 6, 4, 4};
__constant__ int FM_OFF[6]  = {0, 5776, 7942, 8542, 8692, 8728};

__device__ __forceinline__ void geom(const float4 axy, const float4 g,
                                     float area_a, float ag,
                                     float& inter, float& uni) {
    float ltx = fmaxf(axy.x, g.x);
    float lty = fmaxf(axy.y, g.y);
    float rbx = fminf(axy.z, g.z);
    float rby = fminf(axy.w, g.w);
    float w = fmaxf(rbx - ltx, 0.0f);
    float h = fmaxf(rby - lty, 0.0f);
    inter = w * h;
    uni = area_a + ag - inter;       // uni >= max area > 0 always
}

__device__ __forceinline__ float4 enc_box(const float4 g, const float4 anc) {
    float gcx = (g.x + g.z) * 0.5f;
    float gcy = (g.y + g.w) * 0.5f;
    float gw  = g.z - g.x;
    float gh  = g.w - g.y;
    return make_float4((gcx - anc.x) / anc.z,
                       (gcy - anc.y) / anc.w,
                       logf((gw + EPS_F) / (anc.z + EPS_F)),
                       logf((gh + EPS_F) / (anc.w + EPS_F)));
}

// ---------------------------------------------------------------------------
// Prior: ONE WAVE per (b,n). Lanes split 110 genuine candidates (center cell
// all 6 maps + 3x3 on the two finest); rcp-approx, butterfly fmax, lane0
// stores deflated bits into colmax high word (low=0 loses all ties to
// genuine submissions, which carry low>=1).
// ---------------------------------------------------------------------------
__device__ __forceinline__ int prior_cand(int c, float cx, float cy) {
    int f, k, di, dj;
    if (c < 36)       { f = 0; k = c & 3;  int cl = c >> 2;      di = cl / 3 - 1; dj = cl % 3 - 1; }
    else if (c < 90)  { int t = c - 36; f = 1; k = t % 6; int cl = t / 6; di = cl / 3 - 1; dj = cl % 3 - 1; }
    else if (c < 96)  { f = 2; k = c - 90;  di = 0; dj = 0; }
    else if (c < 102) { f = 3; k = c - 96;  di = 0; dj = 0; }
    else if (c < 106) { f = 4; k = c - 102; di = 0; dj = 0; }
    else              { f = 5; k = c - 106; di = 0; dj = 0; }
    int s = FM_SIZE[f];
    int j = (int)(cx * (float)s); j = j < s - 1 ? j : s - 1;
    int i = (int)(cy * (float)s); i = i < s - 1 ? i : s - 1;
    j += dj; i += di;
    if (j < 0 || j >= s || i < 0 || i >= s) return -1;
    return FM_OFF[f] + (i * s + j) * FM_NF[f] + k;
}

__global__ __launch_bounds__(256) void prior_kernel(
        const float4* __restrict__ gt_boxes,
        const float4* __restrict__ anchors_xyxy,
        unsigned long long* __restrict__ colmax) {
    const int b = blockIdx.y;
    const int n = blockIdx.x * 4 + (threadIdx.x >> 6);   // 25*4 = 100
    const int lane = threadIdx.x & 63;
    float4 g = gt_boxes[b * NN + n];
    float ag = (g.z - g.x) * (g.w - g.y);
    float cx = (g.x + g.z) * 0.5f;
    float cy = (g.y + g.w) * 0.5f;
    float best = 0.0f;
    for (int c = lane; c < 110; c += 64) {
        int ai = prior_cand(c, cx, cy);
        if (ai >= 0) {
            float4 an = anchors_xyxy[ai];
            float area_a = (an.z - an.x) * (an.w - an.y);
            float inter, uni;
            geom(an, g, area_a, ag, inter, uni);
            best = fmaxf(best, inter * __builtin_amdgcn_rcpf(uni));
        }
    }
    #pragma unroll
    for (int off = 32; off > 0; off >>= 1)
        best = fmaxf(best, __shfl_xor(best, off));
    if (lane == 0) {
        float defl = best * DEFL;    // <= true colmax*(1-3.2e-7): safe bound
        colmax[b * NN + n] =
            ((unsigned long long)__float_as_uint(defl)) << 32;
    }
}

// ---------------------------------------------------------------------------
// Phase A chunk [N0,N1): branch-free, transcendental-free, wave-op-free.
// Row filter (cross-mult): flag n iff inter*ubest >= ibest*uni*FDEFL
//   (reals: iou_n >= running best => flagged; margin covers both roundings).
// Col filter: flag n iff inter >= filt_n * uni (filt pre-deflated at the
//   snapshot read => true column winner always flagged). Fully unrolled.
// ---------------------------------------------------------------------------
template <int N0, int N1>
__device__ __forceinline__ void passChunk(
        const float4 axy, const float area_a,
        const float4* __restrict__ sg, const float2* __restrict__ sap,
        float& ibest, float& ubest, unsigned& rm, unsigned& cm)
{
    #pragma unroll
    for (int n = N0; n < N1; n++) {
        float4 g = sg[n];
        float2 ar = sap[n];                    // x=area_g, y=deflated filter
        float inter, uni;
        geom(axy, g, area_a, ar.x, inter, uni);
        float p1 = inter * ubest;
        float p2 = ibest * uni;
        bool fl = (inter > 0.0f) && (p1 >= p2 * FDEFL);
        rm |= (fl ? 1u : 0u) << (n - N0);
        bool up = p1 > p2;
        ibest = up ? inter : ibest;
        ubest = up ? uni : ubest;
        bool cf = inter >= ar.y * uni;
        cm |= (cf ? 1u : 0u) << (n - N0);
    }
}

// ---------------------------------------------------------------------------
// Fused IoU pass. Post-loop: row replay (exact div per flagged bit,
// ascending n + strict > == numpy first occurrence); column processing
// (wave-OR'd bits, exact div + packed u64 butterfly ((bits<<32)|(AA-a):
// max iou then lowest a), lane0 atomicMax). FUSED epilogue writes the three
// outputs directly; fallback writes the slot word for scatter+encode.
// ---------------------------------------------------------------------------
template <bool FUSED>
__global__ __launch_bounds__(256) void iou_pass_kernel(
        const float4* __restrict__ gt_boxes,
        const int*    __restrict__ gt_labels,
        const float4* __restrict__ anchors_xyxy,
        const float4* __restrict__ anchors_cxcywh,
        unsigned long long* __restrict__ colmax,    // prior-initialized
        float* __restrict__ out,
        int* __restrict__ out_slot)                 // fallback only
{
    const int b = blockIdx.y;
    const int tid = threadIdx.x;
    const int a = blockIdx.x * 256 + tid;
    const bool valid = (a < AA);
    const int ac = valid ? a : (AA - 1);

    __shared__ float4 sg[NN];
    __shared__ float2 sap[NN];     // x=area_g, y=DEFLATED column filter
    __shared__ int    slab[NN];

    if (tid < NN) {
        float4 g = gt_boxes[b * NN + tid];
        sg[tid] = g;
        // Snapshot colmax hi (prior or concurrently-warmed genuine value).
        // MUST deflate here: warmed bits are exact fl(I/U) and fl(iou*U) can
        // exceed I by 1 ulp, silently dropping tied-lower-index winners
        // (the r14 bug). hi*DEFL is a rigorous lower bound either way.
        unsigned hi = (unsigned)(colmax[b * NN + tid] >> 32);
        sap[tid] = make_float2((g.z - g.x) * (g.w - g.y),
                               __uint_as_float(hi) * DEFL);
        if (FUSED) slab[tid] = gt_labels[b * NN + tid];
    }
    __syncthreads();

    const float4 axy = anchors_xyxy[ac];
    const float area_a = (axy.z - axy.x) * (axy.w - axy.y);
    const unsigned lowkey = (unsigned)(AA - ac);   // bigger = lower anchor

    // ---------------- Phase A ----------------
    float ibest = 0.0f, ubest = 1.0f;
    unsigned rm0 = 0, rm1 = 0, rm2 = 0, rm3 = 0;
    unsigned cm0 = 0, cm1 = 0, cm2 = 0, cm3 = 0;
    passChunk<0, 32>(axy, area_a, sg, sap, ibest, ubest, rm0, cm0);
    passChunk<32, 64>(axy, area_a, sg, sap, ibest, ubest, rm1, cm1);
    passChunk<64, 96>(axy, area_a, sg, sap, ibest, ubest, rm2, cm2);
    passChunk<96, NN>(axy, area_a, sg, sap, ibest, ubest, rm3, cm3);

    // ---------------- Row replay: exact div on flagged bits ---------------
    float bv = 0.0f;   // all-zero row: bv=0, bi=0 == numpy argmax
    int bi = 0;
    {
        unsigned rms[4] = {rm0, rm1, rm2, rm3};
        #pragma unroll
        for (int h = 0; h < 4; h++) {
            unsigned m = rms[h];
            const int nb = h * 32;
            while (m) {
                int n = __builtin_ctz(m) + nb;       // ascending: numpy order
                m &= m - 1;
                float inter, uni;
                geom(axy, sg[n], area_a, sap[n].x, inter, uni);
                float iou = inter / uni;             // exact IEEE == numpy
                if (iou > bv) { bv = iou; bi = n; }  // strict >: first max
            }
        }
    }

    // ---------------- Column processing (post-loop, rare) -----------------
    {
        unsigned cms[4] = {cm0, cm1, cm2, cm3};
        #pragma unroll
        for (int h = 0; h < 4; h++) {
            unsigned wc = cms[h];
            #pragma unroll
            for (int off = 32; off > 0; off >>= 1)
                wc |= __shfl_xor(wc, off);           // wave-OR (uniform)
            const int nb = h * 32;
            while (wc) {
                int n = __builtin_ctz(wc) + nb;
                wc &= wc - 1;
                float inter, uni;
                geom(axy, sg[n], area_a, sap[n].x, inter, uni);
                bool cc = inter >= sap[n].y * uni;
                float iou = inter / uni;             // exact IEEE == numpy
                unsigned long long p = cc
                    ? ((((unsigned long long)__float_as_uint(iou)) << 32) |
                       (unsigned long long)lowkey) : 0ull;
                #pragma unroll
                for (int off = 32; off > 0; off >>= 1) {
                    unsigned long long o = __shfl_xor(p, off);
                    p = o > p ? o : p;
                }
                if ((tid & 63) == 0 && p != 0ull)
                    atomicMax(colmax + b * NN + n, p);
            }
        }
    }

    if (!valid) return;
    const size_t BA = (size_t)BB * AA;
    const size_t base = (size_t)b * AA + a;
    const bool pos = bv > 0.5f;                      // exact bv decision
    if (FUSED) {
        out[base] = pos ? (float)slab[bi] : 0.0f;                // labels
        ((float4*)(out + BA))[base] = enc_box(sg[bi], anchors_cxcywh[a]);
        out[5 * BA + base] = pos ? 1.0f : 0.0f;                  // mask
    } else {
        out_slot[base] = bi | (pos ? POS_BIT : 0);
    }
}

// ---------------------------------------------------------------------------
// FUSED path: fix overridden anchors. Winner for anchor a = LAST n with
// colmax(b,n) -> a (numpy fancy-assignment last-n-wins), checked in-block.
// Runs after iou_pass (kernel boundary = full sync); per-anchor-unique writes.
// ---------------------------------------------------------------------------
__global__ void override_kernel(const unsigned long long* __restrict__ colmax,
                                const float4* __restrict__ gt_boxes,
                                const int*    __restrict__ gt_labels,
                                const float4* __restrict__ anchors_cxcywh,
                                float* __restrict__ out) {
    const int b = blockIdx.x;
    const int n = threadIdx.x;
    __shared__ int sa[NN];
    int an = -1;
    if (n < NN) {
        unsigned long long v = colmax[b * NN + n];
        unsigned low = (unsigned)(v & 0xFFFFFFFFull);
        if (low >= 1u && low <= (unsigned)AA) an = AA - (int)low;
        sa[n] = an;
    }
    __syncthreads();
    if (n >= NN || an < 0) return;
    for (int n2 = n + 1; n2 < NN; n2++)
        if (sa[n2] == an) return;                    // later n wins
    const size_t BA = (size_t)BB * AA;
    const size_t base = (size_t)b * AA + an;
    out[base] = (float)gt_labels[b * NN + n];                    // label
    ((float4*)(out + BA))[base] =
        enc_box(gt_boxes[b * NN + n], anchors_cxcywh[an]);       // box
    out[5 * BA + base] = 1.0f;                                   // mask
}

// ---------------------------------------------------------------------------
// FALLBACK path kernels (r12-proven): scatter + encode via slot word.
// ---------------------------------------------------------------------------
__global__ void scatter_kernel(const unsigned long long* __restrict__ colmax,
                               int* __restrict__ out_slot) {
    const int b = blockIdx.x;
    const int n = threadIdx.x;
    if (n < NN) {
        unsigned long long v = colmax[b * NN + n];
        unsigned low = (unsigned)(v & 0xFFFFFFFFull);
        if (low >= 1u && low <= (unsigned)AA) {
            int idx = AA - (int)low;
            atomicMax(&out_slot[(size_t)b * AA + idx], OVR_FLAG + n);
        }
    }
}

__global__ __launch_bounds__(256) void encode_kernel(
        const int* __restrict__ gt_labels,
        const float4* __restrict__ gt_boxes,
        const float4* __restrict__ anchors_cxcywh,
        float* __restrict__ out) {
    const int b = blockIdx.y;
    const int tid = threadIdx.x;
    const int a = blockIdx.x * 256 + tid;
    __shared__ float4 sg[NN];
    __shared__ int    slab[NN];
    if (tid < NN) {
        sg[tid]   = gt_boxes[b * NN + tid];
        slab[tid] = gt_labels[b * NN + tid];
    }
    __syncthreads();
    if (a >= AA) return;
    const size_t BA = (size_t)BB * AA;
    const size_t base = (size_t)b * AA + a;
    int s = ((const int*)(out + 5 * BA))[base];
    int idx; bool pos;
    if (s >= OVR_FLAG) { idx = s - OVR_FLAG;  pos = true; }
    else               { idx = s & 0x7FFF;    pos = (s & POS_BIT) != 0; }
    out[base] = pos ? (float)slab[idx] : 0.0f;
    ((float4*)(out + BA))[base] = enc_box(sg[idx], anchors_cxcywh[a]);
    out[5 * BA + base] = pos ? 1.0f : 0.0f;
}

extern "C" void kernel_launch(void* const* d_in, const int* in_sizes, int n_in,
                              void* d_out, int out_size, void* d_ws, size_t ws_size,
                              hipStream_t stream) {
    const int*    gt_labels    = (const int*)d_in[0];
    const float4* gt_boxes     = (const float4*)d_in[1];
    const float4* anchors_cxcy = (const float4*)d_in[2];
    const float4* anchors_xyxy = (const float4*)d_in[3];
    float* out = (float*)d_out;

    const size_t BA = (size_t)BB * AA;
    const size_t colmax_bytes = (size_t)BB * NN * sizeof(unsigned long long);
    const bool fused = (ws_size >= colmax_bytes);
    unsigned long long* colmax = fused
        ? (unsigned long long*)d_ws
        : (unsigned long long*)(out + BA);          // r12-proven fallback spot
    int* slot = (int*)(out + 5 * BA);

    dim3 pgrid(25, BB);                              // wave per (b,n)
    prior_kernel<<<pgrid, 256, 0, stream>>>(gt_boxes, anchors_xyxy, colmax);

    dim3 grid((AA + 255) / 256, BB);                 // (35, 64)
    if (fused) {
        iou_pass_kernel<true><<<grid, 256, 0, stream>>>(
            gt_boxes, gt_labels, anchors_xyxy, anchors_cxcy, colmax, out, slot);
        override_kernel<<<BB, 128, 0, stream>>>(colmax, gt_boxes, gt_labels,
                                                anchors_cxcy, out);
    } else {
        iou_pass_kernel<false><<<grid, 256, 0, stream>>>(
            gt_boxes, gt_labels, anchors_xyxy, anchors_cxcy, colmax, out, slot);
        scatter_kernel<<<BB, 128, 0, stream>>>(colmax, slot);
        encode_kernel<<<grid, 256, 0, stream>>>(gt_labels, gt_boxes,
                                                anchors_cxcy, out);
    }
}

// Round 16
// 132.525 us; speedup vs baseline: 1.6911x; 1.6911x over previous
//
#include <hip/hip_runtime.h>
#include <math.h>

// CRITICAL: ban FMA contraction file-wide. 1-ulp iou shifts flip near-tie
// argmaxes vs numpy's correctly-rounded ref (rounds 2-4, absmax 69).
#pragma clang fp contract(off)

// Shapes: B=64, N=100, A=8732.
// Out layout (f32 flat): [0,BA) labels | [BA,5BA) boxes | [5BA,6BA) mask
// FUSED path (ws_size >= 51200): colmax u64[B*N] in d_ws; iou_pass writes
// the final outputs directly; override_kernel fixes overridden anchors.
// FALLBACK path: colmax at out+BA, slot in mask region, scatter+encode (r12).
//
// R15 LESSON (counters: VGPR=256, occupancy 9.7%, 157 us): full unroll of the
// barrier-free Phase A let the compiler hoist ~100 iterations of LDS loads
// into registers -> spill cliff. Containment: #pragma unroll 4 (loads can't
// be hoisted past the unroll window) + __launch_bounds__(256,4) (VGPR<=128).

#define AA 8732
#define NN 100
#define BB 64
#define EPS_F 1e-6f
#define OVR_FLAG 0x10000
#define POS_BIT  0x8000
// One-sided-bound margins (HW-validated r8-r15):
// DEFL deflates filter bounds (rcp err / snapshot slack + margin);
// FDEFL covers the two f32 product roundings in cross-mult compares.
// Deflate at EVERY filter read site (r14 bug: undeflated colmax snapshot
// dropped tied-lower-index winners; r15 proved the fix).
#define DEFL  0.9999995f
#define FDEFL 0.9999996f

__constant__ int FM_SIZE[6] = {38, 19, 10, 5, 3, 1};
__constant__ int FM_NF[6]   = {4, 6, 6, 6, 4, 4};
__constant__ int FM_OFF[6]  = {0, 5776, 7942, 8542, 8692, 8728};

__device__ __forceinline__ void geom(const float4 axy, const float4 g,
                                     float area_a, float ag,
                                     float& inter, float& uni) {
    float ltx = fmaxf(axy.x, g.x);
    float lty = fmaxf(axy.y, g.y);
    float rbx = fminf(axy.z, g.z);
    float rby = fminf(axy.w, g.w);
    float w = fmaxf(rbx - ltx, 0.0f);
    float h = fmaxf(rby - lty, 0.0f);
    inter = w * h;
    uni = area_a + ag - inter;       // uni >= max area > 0 always
}

__device__ __forceinline__ float4 enc_box(const float4 g, const float4 anc) {
    float gcx = (g.x + g.z) * 0.5f;
    float gcy = (g.y + g.w) * 0.5f;
    float gw  = g.z - g.x;
    float gh  = g.w - g.y;
    return make_float4((gcx - anc.x) / anc.z,
                       (gcy - anc.y) / anc.w,
                       logf((gw + EPS_F) / (anc.z + EPS_F)),
                       logf((gh + EPS_F) / (anc.w + EPS_F)));
}

// ---------------------------------------------------------------------------
// Prior: ONE WAVE per (b,n). Lanes split 110 genuine candidates (center cell
// all 6 maps + 3x3 on the two finest); rcp-approx, butterfly fmax, lane0
// stores deflated bits into colmax high word (low=0 loses all ties to
// genuine submissions, which carry low>=1). [HW-validated r15]
// ---------------------------------------------------------------------------
__device__ __forceinline__ int prior_cand(int c, float cx, float cy) {
    int f, k, di, dj;
    if (c < 36)       { f = 0; k = c & 3;  int cl = c >> 2;      di = cl / 3 - 1; dj = cl % 3 - 1; }
    else if (c < 90)  { int t = c - 36; f = 1; k = t % 6; int cl = t / 6; di = cl / 3 - 1; dj = cl % 3 - 1; }
    else if (c < 96)  { f = 2; k = c - 90;  di = 0; dj = 0; }
    else if (c < 102) { f = 3; k = c - 96;  di = 0; dj = 0; }
    else if (c < 106) { f = 4; k = c - 102; di = 0; dj = 0; }
    else              { f = 5; k = c - 106; di = 0; dj = 0; }
    int s = FM_SIZE[f];
    int j = (int)(cx * (float)s); j = j < s - 1 ? j : s - 1;
    int i = (int)(cy * (float)s); i = i < s - 1 ? i : s - 1;
    j += dj; i += di;
    if (j < 0 || j >= s || i < 0 || i >= s) return -1;
    return FM_OFF[f] + (i * s + j) * FM_NF[f] + k;
}

__global__ __launch_bounds__(256) void prior_kernel(
        const float4* __restrict__ gt_boxes,
        const float4* __restrict__ anchors_xyxy,
        unsigned long long* __restrict__ colmax) {
    const int b = blockIdx.y;
    const int n = blockIdx.x * 4 + (threadIdx.x >> 6);   // 25*4 = 100
    const int lane = threadIdx.x & 63;
    float4 g = gt_boxes[b * NN + n];
    float ag = (g.z - g.x) * (g.w - g.y);
    float cx = (g.x + g.z) * 0.5f;
    float cy = (g.y + g.w) * 0.5f;
    float best = 0.0f;
    for (int c = lane; c < 110; c += 64) {
        int ai = prior_cand(c, cx, cy);
        if (ai >= 0) {
            float4 an = anchors_xyxy[ai];
            float area_a = (an.z - an.x) * (an.w - an.y);
            float inter, uni;
            geom(an, g, area_a, ag, inter, uni);
            best = fmaxf(best, inter * __builtin_amdgcn_rcpf(uni));
        }
    }
    #pragma unroll
    for (int off = 32; off > 0; off >>= 1)
        best = fmaxf(best, __shfl_xor(best, off));
    if (lane == 0) {
        float defl = best * DEFL;    // <= true colmax*(1-3.2e-7): safe bound
        colmax[b * NN + n] =
            ((unsigned long long)__float_as_uint(defl)) << 32;
    }
}

// ---------------------------------------------------------------------------
// Phase A chunk [N0,N1): branch-free, transcendental-free, wave-op-free.
// Row filter (cross-mult): flag n iff inter*ubest >= ibest*uni*FDEFL.
// Col filter: flag n iff inter >= filt_n * uni (filt deflated at snapshot).
// #pragma unroll 4: bounds LDS-load hoisting to a 4-iter window (VGPR
// containment — the r15 fix). Variable mask shift costs 1 extra inst.
// ---------------------------------------------------------------------------
template <int N0, int N1>
__device__ __forceinline__ void passChunk(
        const float4 axy, const float area_a,
        const float4* __restrict__ sg, const float2* __restrict__ sap,
        float& ibest, float& ubest, unsigned& rm, unsigned& cm)
{
    #pragma unroll 4
    for (int n = N0; n < N1; n++) {
        float4 g = sg[n];
        float2 ar = sap[n];                    // x=area_g, y=deflated filter
        float inter, uni;
        geom(axy, g, area_a, ar.x, inter, uni);
        float p1 = inter * ubest;
        float p2 = ibest * uni;
        bool fl = (inter > 0.0f) && (p1 >= p2 * FDEFL);
        rm |= (fl ? 1u : 0u) << (n - N0);
        bool up = p1 > p2;
        ibest = up ? inter : ibest;
        ubest = up ? uni : ubest;
        bool cf = inter >= ar.y * uni;
        cm |= (cf ? 1u : 0u) << (n - N0);
    }
}

// ---------------------------------------------------------------------------
// Fused IoU pass. Post-loop: row replay (exact div per flagged bit,
// ascending n + strict > == numpy first occurrence); column processing
// (wave-OR'd bits, exact div + packed u64 butterfly ((bits<<32)|(AA-a):
// max iou then lowest a), lane0 atomicMax). FUSED epilogue writes the three
// outputs directly; fallback writes the slot word for scatter+encode.
// __launch_bounds__(256,4): VGPR cap 128 (16 waves/CU floor).
// ---------------------------------------------------------------------------
template <bool FUSED>
__global__ __launch_bounds__(256, 4) void iou_pass_kernel(
        const float4* __restrict__ gt_boxes,
        const int*    __restrict__ gt_labels,
        const float4* __restrict__ anchors_xyxy,
        const float4* __restrict__ anchors_cxcywh,
        unsigned long long* __restrict__ colmax,    // prior-initialized
        float* __restrict__ out,
        int* __restrict__ out_slot)                 // fallback only
{
    const int b = blockIdx.y;
    const int tid = threadIdx.x;
    const int a = blockIdx.x * 256 + tid;
    const bool valid = (a < AA);
    const int ac = valid ? a : (AA - 1);

    __shared__ float4 sg[NN];
    __shared__ float2 sap[NN];     // x=area_g, y=DEFLATED column filter
    __shared__ int    slab[NN];

    if (tid < NN) {
        float4 g = gt_boxes[b * NN + tid];
        sg[tid] = g;
        // Deflate the colmax-hi snapshot at the read site (r14 bug / r15 fix)
        unsigned hi = (unsigned)(colmax[b * NN + tid] >> 32);
        sap[tid] = make_float2((g.z - g.x) * (g.w - g.y),
                               __uint_as_float(hi) * DEFL);
        if (FUSED) slab[tid] = gt_labels[b * NN + tid];
    }
    __syncthreads();

    const float4 axy = anchors_xyxy[ac];
    const float area_a = (axy.z - axy.x) * (axy.w - axy.y);
    const unsigned lowkey = (unsigned)(AA - ac);   // bigger = lower anchor

    // ---------------- Phase A ----------------
    float ibest = 0.0f, ubest = 1.0f;
    unsigned rm0 = 0, rm1 = 0, rm2 = 0, rm3 = 0;
    unsigned cm0 = 0, cm1 = 0, cm2 = 0, cm3 = 0;
    passChunk<0, 32>(axy, area_a, sg, sap, ibest, ubest, rm0, cm0);
    passChunk<32, 64>(axy, area_a, sg, sap, ibest, ubest, rm1, cm1);
    passChunk<64, 96>(axy, area_a, sg, sap, ibest, ubest, rm2, cm2);
    passChunk<96, NN>(axy, area_a, sg, sap, ibest, ubest, rm3, cm3);

    // ---------------- Row replay: exact div on flagged bits ---------------
    float bv = 0.0f;   // all-zero row: bv=0, bi=0 == numpy argmax
    int bi = 0;
    {
        unsigned rms[4] = {rm0, rm1, rm2, rm3};
        #pragma unroll
        for (int h = 0; h < 4; h++) {
            unsigned m = rms[h];
            const int nb = h * 32;
            while (m) {
                int n = __builtin_ctz(m) + nb;       // ascending: numpy order
                m &= m - 1;
                float inter, uni;
                geom(axy, sg[n], area_a, sap[n].x, inter, uni);
                float iou = inter / uni;             // exact IEEE == numpy
                if (iou > bv) { bv = iou; bi = n; }  // strict >: first max
            }
        }
    }

    // ---------------- Column processing (post-loop, rare) -----------------
    {
        unsigned cms[4] = {cm0, cm1, cm2, cm3};
        #pragma unroll
        for (int h = 0; h < 4; h++) {
            unsigned wc = cms[h];
            #pragma unroll
            for (int off = 32; off > 0; off >>= 1)
                wc |= __shfl_xor(wc, off);           // wave-OR (uniform)
            const int nb = h * 32;
            while (wc) {
                int n = __builtin_ctz(wc) + nb;
                wc &= wc - 1;
                float inter, uni;
                geom(axy, sg[n], area_a, sap[n].x, inter, uni);
                bool cc = inter >= sap[n].y * uni;
                float iou = inter / uni;             // exact IEEE == numpy
                unsigned long long p = cc
                    ? ((((unsigned long long)__float_as_uint(iou)) << 32) |
                       (unsigned long long)lowkey) : 0ull;
                #pragma unroll
                for (int off = 32; off > 0; off >>= 1) {
                    unsigned long long o = __shfl_xor(p, off);
                    p = o > p ? o : p;
                }
                if ((tid & 63) == 0 && p != 0ull)
                    atomicMax(colmax + b * NN + n, p);
            }
        }
    }

    if (!valid) return;
    const size_t BA = (size_t)BB * AA;
    const size_t base = (size_t)b * AA + a;
    const bool pos = bv > 0.5f;                      // exact bv decision
    if (FUSED) {
        out[base] = pos ? (float)slab[bi] : 0.0f;                // labels
        ((float4*)(out + BA))[base] = enc_box(sg[bi], anchors_cxcywh[a]);
        out[5 * BA + base] = pos ? 1.0f : 0.0f;                  // mask
    } else {
        out_slot[base] = bi | (pos ? POS_BIT : 0);
    }
}

// ---------------------------------------------------------------------------
// FUSED path: fix overridden anchors. Winner for anchor a = LAST n with
// colmax(b,n) -> a (numpy last-n-wins), checked in-block. [HW-validated r15]
// ---------------------------------------------------------------------------
__global__ void override_kernel(const unsigned long long* __restrict__ colmax,
                                const float4* __restrict__ gt_boxes,
                                const int*    __restrict__ gt_labels,
                                const float4* __restrict__ anchors_cxcywh,
                                float* __restrict__ out) {
    const int b = blockIdx.x;
    const int n = threadIdx.x;
    __shared__ int sa[NN];
    int an = -1;
    if (n < NN) {
        unsigned long long v = colmax[b * NN + n];
        unsigned low = (unsigned)(v & 0xFFFFFFFFull);
        if (low >= 1u && low <= (unsigned)AA) an = AA - (int)low;
        sa[n] = an;
    }
    __syncthreads();
    if (n >= NN || an < 0) return;
    for (int n2 = n + 1; n2 < NN; n2++)
        if (sa[n2] == an) return;                    // later n wins
    const size_t BA = (size_t)BB * AA;
    const size_t base = (size_t)b * AA + an;
    out[base] = (float)gt_labels[b * NN + n];                    // label
    ((float4*)(out + BA))[base] =
        enc_box(gt_boxes[b * NN + n], anchors_cxcywh[an]);       // box
    out[5 * BA + base] = 1.0f;                                   // mask
}

// ---------------------------------------------------------------------------
// FALLBACK path kernels (r12-proven): scatter + encode via slot word.
// ---------------------------------------------------------------------------
__global__ void scatter_kernel(const unsigned long long* __restrict__ colmax,
                               int* __restrict__ out_slot) {
    const int b = blockIdx.x;
    const int n = threadIdx.x;
    if (n < NN) {
        unsigned long long v = colmax[b * NN + n];
        unsigned low = (unsigned)(v & 0xFFFFFFFFull);
        if (low >= 1u && low <= (unsigned)AA) {
            int idx = AA - (int)low;
            atomicMax(&out_slot[(size_t)b * AA + idx], OVR_FLAG + n);
        }
    }
}

__global__ __launch_bounds__(256) void encode_kernel(
        const int* __restrict__ gt_labels,
        const float4* __restrict__ gt_boxes,
        const float4* __restrict__ anchors_cxcywh,
        float* __restrict__ out) {
    const int b = blockIdx.y;
    const int tid = threadIdx.x;
    const int a = blockIdx.x * 256 + tid;
    __shared__ float4 sg[NN];
    __shared__ int    slab[NN];
    if (tid < NN) {
        sg[tid]   = gt_boxes[b * NN + tid];
        slab[tid] = gt_labels[b * NN + tid];
    }
    __syncthreads();
    if (a >= AA) return;
    const size_t BA = (size_t)BB * AA;
    const size_t base = (size_t)b * AA + a;
    int s = ((const int*)(out + 5 * BA))[base];
    int idx; bool pos;
    if (s >= OVR_FLAG) { idx = s - OVR_FLAG;  pos = true; }
    else               { idx = s & 0x7FFF;    pos = (s & POS_BIT) != 0; }
    out[base] = pos ? (float)slab[idx] : 0.0f;
    ((float4*)(out + BA))[base] = enc_box(sg[idx], anchors_cxcywh[a]);
    out[5 * BA + base] = pos ? 1.0f : 0.0f;
}

extern "C" void kernel_launch(void* const* d_in, const int* in_sizes, int n_in,
                              void* d_out, int out_size, void* d_ws, size_t ws_size,
                              hipStream_t stream) {
    const int*    gt_labels    = (const int*)d_in[0];
    const float4* gt_boxes     = (const float4*)d_in[1];
    const float4* anchors_cxcy = (const float4*)d_in[2];
    const float4* anchors_xyxy = (const float4*)d_in[3];
    float* out = (float*)d_out;

    const size_t BA = (size_t)BB * AA;
    const size_t colmax_bytes = (size_t)BB * NN * sizeof(unsigned long long);
    const bool fused = (ws_size >= colmax_bytes);
    unsigned long long* colmax = fused
        ? (unsigned long long*)d_ws
        : (unsigned long long*)(out + BA);          // r12-proven fallback spot
    int* slot = (int*)(out + 5 * BA);

    dim3 pgrid(25, BB);                              // wave per (b,n)
    prior_kernel<<<pgrid, 256, 0, stream>>>(gt_boxes, anchors_xyxy, colmax);

    dim3 grid((AA + 255) / 256, BB);                 // (35, 64)
    if (fused) {
        iou_pass_kernel<true><<<grid, 256, 0, stream>>>(
            gt_boxes, gt_labels, anchors_xyxy, anchors_cxcy, colmax, out, slot);
        override_kernel<<<BB, 128, 0, stream>>>(colmax, gt_boxes, gt_labels,
                                                anchors_cxcy, out);
    } else {
        iou_pass_kernel<false><<<grid, 256, 0, stream>>>(
            gt_boxes, gt_labels, anchors_xyxy, anchors_cxcy, colmax, out, slot);
        scatter_kernel<<<BB, 128, 0, stream>>>(colmax, slot);
        encode_kernel<<<grid, 256, 0, stream>>>(gt_labels, gt_boxes,
                                                anchors_cxcy, out);
    }
}